// Round 7
// baseline (204.214 us; speedup 1.0000x reference)
//
#include <hip/hip_runtime.h>

// ---------------------------------------------------------------------------
// Attention (b=2, sq=skv=2048, dim=1024, H=16, DH=64) for MI355X / gfx950.
// fp32 -> bf16 internal -> fp32 out.  5 dispatches this round:
//   prep | fused QKV GEMM | attn x2 (bh split) | GEMM out
// R16: VISIBILITY round.  attn reverted to R14 (measured best 44.9us; R15
//   interleave regressed to 47.7).  attn split into two 256-block
//   dispatches (bh 0..15 / 16..31) so each runs ~24us -> prep/gemm_qkv/
//   gemm_out surface in rocprof top-5 with counters.  Non-attn has been
//   stuck at ~136us vs ~50us roofline for 7 rounds; need to see WHERE.
// ---------------------------------------------------------------------------

typedef __attribute__((ext_vector_type(8))) short short8;   // 8 x bf16
typedef __attribute__((ext_vector_type(4))) short short4v;  // 4 x bf16 (8B)
typedef __attribute__((ext_vector_type(4))) float floatx4;  // MFMA accum 16x16
typedef __attribute__((ext_vector_type(16))) float floatx16; // MFMA accum 32x32

#define QSCALE 0.18033688f  /* 0.125 * log2(e) folded into Q */

#if __has_builtin(__builtin_amdgcn_exp2f)
#define EXP2(x) __builtin_amdgcn_exp2f(x)
#else
#define EXP2(x) exp2f(x)
#endif

__device__ __forceinline__ ushort f2b(float f) {  // fp32 -> bf16 RNE
  union { float f; unsigned u; } x; x.f = f;
  unsigned r = (x.u + 0x7fffu + ((x.u >> 16) & 1u)) >> 16;
  return (ushort)r;
}

// pack two fp32 -> two bf16 in one uint via v_perm (round-half-up)
__device__ __forceinline__ unsigned f2b2(float a, float b) {
  union { float f; unsigned u; } x, y; x.f = a; y.f = b;
  return __builtin_amdgcn_perm(y.u + 0x8000u, x.u + 0x8000u, 0x07060302u);
}

// pack two fp32 -> two bf16 (RNE), single instruction; a -> low ushort
__device__ __forceinline__ unsigned cvtpk(float a, float b) {
  unsigned r;
  asm("v_cvt_pk_bf16_f32 %0, %1, %2" : "=v"(r) : "v"(a), "v"(b));
  return r;
}

#define GLL(gp, lp)                                                            \
  __builtin_amdgcn_global_load_lds(                                            \
      (const __attribute__((address_space(1))) void*)(gp),                     \
      (__attribute__((address_space(3))) void*)(lp), 16, 0, 0)

// ---- prep: activations fp32->bf16 (blocks 0..2047) + W transpose (rest) ----
__global__ void prep(const float* __restrict__ xq, const float* __restrict__ xkv,
                     ushort* __restrict__ oq, ushort* __restrict__ okv,
                     const float* __restrict__ Wqkv, ushort* __restrict__ WqkvT,
                     const float* __restrict__ Wout, ushort* __restrict__ WoutT) {
  __shared__ float tile[32][33];
  int bid = blockIdx.x;
  const int n = 4096 * 1024;
  if (bid < 2048) {
    bool lo = bid < 1024;
    const float* in = lo ? xq : xkv;
    ushort* out = lo ? oq : okv;
    int b2 = lo ? bid : bid - 1024;
    int stride = 1024 * 256 * 4;
    for (int i = (b2 * 256 + (int)threadIdx.x) * 4; i < n; i += stride) {
      float4 v = *(const float4*)(in + i);
      uint2 o;
      o.x = cvtpk(v.x, v.y);
      o.y = cvtpk(v.z, v.w);
      *(uint2*)(out + i) = o;
    }
    return;
  }
  // transpose blocks: 4096 tiles of 32x32 (96+32 cols x 32 rows of k)
  int tb = bid - 2048;               // 0..4095
  int bx = tb & 127, by = tb >> 7;   // bx: 0..95 Wqkv, 96..127 Wout
  bool first = bx < 96;
  const float* in = first ? Wqkv : Wout;
  ushort* out = first ? WqkvT : WoutT;
  int N = first ? 3072 : 1024;
  int bxx = first ? bx : bx - 96;
  int k0 = by * 32, n0 = bxx * 32;
  // load: 256 thr = 32 k-rows x 8 float4-cols, coalesced 16B
  {
    int row = threadIdx.x >> 3, c = threadIdx.x & 7;
    float4 v = *(const float4*)(in + (size_t)(k0 + row) * N + n0 + c * 4);
    tile[row][c * 4 + 0] = v.x;
    tile[row][c * 4 + 1] = v.y;
    tile[row][c * 4 + 2] = v.z;
    tile[row][c * 4 + 3] = v.w;
  }
  __syncthreads();
  // store: 256 thr = 16 k-pairs x 16 n-rows, dword (2 bf16) stores
  {
    int tx2 = threadIdx.x & 15, ty2 = threadIdx.x >> 4;
#pragma unroll
    for (int i = 0; i < 2; i++) {
      int nr = ty2 + 16 * i;
      unsigned v = cvtpk(tile[2 * tx2][nr], tile[2 * tx2 + 1][nr]);
      *(unsigned*)(out + (size_t)(n0 + nr) * 1024 + k0 + 2 * tx2) = v;
    }
  }
}

// ---------------- fused QKV GEMM: 128x128 tile, BK=32, dbuf ------------------
// C cols: [0,1024) Q*QSCALE -> Cq ; [1024,2048) K -> Ck ; [2048,3072) V^T -> Cv
// XCD-chunked block swizzle: 768 blocks, 96/XCD.
__global__ __launch_bounds__(256, 3) void gemm_qkv(
    const ushort* __restrict__ Aq, const ushort* __restrict__ Akv,
    const ushort* __restrict__ Bt,
    ushort* __restrict__ Cq, ushort* __restrict__ Ck, ushort* __restrict__ Cv) {
  __shared__ __align__(16) ushort smem[17408];  // 34816 B
  ushort* Asb = smem;          // [2][4096]
  ushort* Bsb = smem + 8192;   // [2][4096]
  // swizzle: lid -> xcd-chunked id; bx 0..23 (n), by 0..31 (m)
  int lid = blockIdx.y * 24 + blockIdx.x;
  int nid = (lid & 7) * 96 + (lid >> 3);
  int bx = nid % 24, by = nid / 24;
  const int n0 = bx * 128, m0 = by * 128;
  // col blocks: 0..7 = Q (from x_q), 8..15 = K, 16..23 = V (both from x_kv)
  const ushort* A = (bx >= 8) ? Akv : Aq;
  const int t = threadIdx.x;
  const int w = t >> 6, lane = t & 63, dl = lane & 15, g = lane >> 4;
  const int wm = (w >> 1) * 64, wn = (w & 1) * 64;
  const int K = 1024;

  auto stage = [&](int buf, int k0) {
#pragma unroll
    for (int p = 0; p < 2; p++) {
      int j = t + p * 256;
      int row = j >> 2, slot = j & 3, c = (slot - row) & 3;
      GLL(A + (size_t)(m0 + row) * K + k0 + c * 8, &Asb[buf * 4096 + j * 8]);
    }
#pragma unroll
    for (int p = 0; p < 2; p++) {
      int j = t + p * 256;
      int row = j >> 2, slot = j & 3, c = (slot - row) & 3;
      GLL(Bt + (size_t)(n0 + row) * K + k0 + c * 8, &Bsb[buf * 4096 + j * 8]);
    }
  };

  const floatx4 fz = {0.f, 0.f, 0.f, 0.f};
  floatx4 acc[4][4];
#pragma unroll
  for (int i = 0; i < 4; i++)
#pragma unroll
    for (int j = 0; j < 4; j++) acc[i][j] = fz;

  stage(0, 0);
  for (int kt = 0; kt < 32; kt++) {
    int cur = kt & 1;
    __builtin_amdgcn_s_waitcnt(0);
    __syncthreads();  // buf[cur] ready; all waves past buf[cur^1] reads
    if (kt + 1 < 32) stage(cur ^ 1, (kt + 1) * 32);
    short8 af[4], bf[4];
#pragma unroll
    for (int mt = 0; mt < 4; mt++) {
      int row = wm + mt * 16 + dl;
      af[mt] = *(const short8*)&Asb[cur * 4096 + row * 32 + ((g + row) & 3) * 8];
    }
#pragma unroll
    for (int nt = 0; nt < 4; nt++) {
      int row = wn + nt * 16 + dl;
      bf[nt] = *(const short8*)&Bsb[cur * 4096 + row * 32 + ((g + row) & 3) * 8];
    }
#pragma unroll
    for (int mt = 0; mt < 4; mt++)
#pragma unroll
      for (int nt = 0; nt < 4; nt++)
        acc[mt][nt] = __builtin_amdgcn_mfma_f32_16x16x32_bf16(af[mt], bf[nt], acc[mt][nt], 0, 0, 0);
  }

  if (bx < 16) {
    // direct store: row = g*4 + r (+16*mt), col = dl (+16*nt)
#pragma unroll
    for (int mt = 0; mt < 4; mt++)
#pragma unroll
      for (int nt = 0; nt < 4; nt++) {
        int gcol = n0 + wn + nt * 16 + dl;
        int row0 = m0 + wm + mt * 16 + g * 4;
        if (gcol < 1024) {  // Q with folded softmax scale
#pragma unroll
          for (int r = 0; r < 4; r++)
            Cq[(size_t)(row0 + r) * 1024 + gcol] =
                (ushort)cvtpk(acc[mt][nt][r] * QSCALE, 0.f);
        } else {
#pragma unroll
          for (int r = 0; r < 4; r++)
            Ck[(size_t)(row0 + r) * 1024 + gcol - 1024] =
                (ushort)cvtpk(acc[mt][nt][r], 0.f);
        }
      }
  } else {
    // V^T via LDS: smem tile [n-local 128][m-local, stride 136] bf16
    __syncthreads();  // all staging reads done; smem reusable
#pragma unroll
    for (int mt = 0; mt < 4; mt++)
#pragma unroll
      for (int nt = 0; nt < 4; nt++) {
        int ncol = wn + nt * 16 + dl;     // hd-local
        int mrow = wm + mt * 16 + g * 4;  // kv-local (4 consecutive)
        uint2 pk;
        pk.x = cvtpk(acc[mt][nt][0], acc[mt][nt][1]);
        pk.y = cvtpk(acc[mt][nt][2], acc[mt][nt][3]);
        *(uint2*)&smem[ncol * 136 + mrow] = pk;
      }
    __syncthreads();
    // coalesced: Cv[b][hd][kv], 2048 chunks of 16B (128 rows x 16 chunks)
    int hd0 = n0 - 2048;            // 0..1023
    int bb = m0 >> 11;              // batch
    int kv0 = m0 & 2047;
#pragma unroll
    for (int p = 0; p < 8; p++) {
      int j = t + p * 256;
      int row = j >> 4, c = j & 15;
      short8 v = *(const short8*)&smem[row * 136 + c * 8];
      *(short8*)(Cv + ((size_t)(bb * 1024 + hd0 + row)) * 2048 + kv0 + c * 8) = v;
    }
  }
}

// ---------------- out GEMM: 128x64 tile, BK=64, dbuf, f32 + bias ------------
__global__ __launch_bounds__(256, 3) void gemm_out(
    const ushort* __restrict__ A, const ushort* __restrict__ Bt,
    float* __restrict__ C, const float* __restrict__ bias) {
  __shared__ __align__(16) ushort As[2][128 * 64];
  __shared__ __align__(16) ushort Bs[2][64 * 64];
  // swizzle: 512 blocks, 64/XCD
  int lid = blockIdx.y * 16 + blockIdx.x;
  int nid = (lid & 7) * 64 + (lid >> 3);
  int bx = nid & 15, by = nid >> 4;
  const int n0 = bx * 64, m0 = by * 128;
  const int t = threadIdx.x;
  const int w = t >> 6, lane = t & 63, dl = lane & 15, g = lane >> 4;
  const int wm = (w >> 1) * 64, wn = (w & 1) * 32;
  const int K = 1024;

  auto stage = [&](int buf, int k0) {
#pragma unroll
    for (int p = 0; p < 4; p++) {
      int j = t + p * 256;
      int row = j >> 3, slot = j & 7, c = (slot - row) & 7;
      GLL(A + (size_t)(m0 + row) * K + k0 + c * 8, &As[buf][j * 8]);
    }
#pragma unroll
    for (int p = 0; p < 2; p++) {
      int j = t + p * 256;
      int row = j >> 3, slot = j & 7, c = (slot - row) & 7;
      GLL(Bt + (size_t)(n0 + row) * K + k0 + c * 8, &Bs[buf][j * 8]);
    }
  };

  const floatx4 fz = {0.f, 0.f, 0.f, 0.f};
  floatx4 acc[4][2];
#pragma unroll
  for (int i = 0; i < 4; i++)
#pragma unroll
    for (int j = 0; j < 2; j++) acc[i][j] = fz;

  stage(0, 0);
  for (int kt = 0; kt < 16; kt++) {
    int cur = kt & 1;
    __builtin_amdgcn_s_waitcnt(0);
    __syncthreads();
    if (kt + 1 < 16) stage(cur ^ 1, (kt + 1) * 64);
#pragma unroll
    for (int ks = 0; ks < 2; ks++) {
      short8 af[4], bf[2];
#pragma unroll
      for (int mt = 0; mt < 4; mt++) {
        int row = wm + mt * 16 + dl;
        af[mt] = *(const short8*)&As[cur][row * 64 + ((ks * 4 + g + row) & 7) * 8];
      }
#pragma unroll
      for (int nt = 0; nt < 2; nt++) {
        int row = wn + nt * 16 + dl;
        bf[nt] = *(const short8*)&Bs[cur][row * 64 + ((ks * 4 + g + row) & 7) * 8];
      }
#pragma unroll
      for (int mt = 0; mt < 4; mt++)
#pragma unroll
        for (int nt = 0; nt < 2; nt++)
          acc[mt][nt] = __builtin_amdgcn_mfma_f32_16x16x32_bf16(af[mt], bf[nt], acc[mt][nt], 0, 0, 0);
    }
  }
#pragma unroll
  for (int mt = 0; mt < 4; mt++)
#pragma unroll
    for (int nt = 0; nt < 2; nt++) {
      int gcol = n0 + wn + nt * 16 + dl;
      int row0 = m0 + wm + mt * 16 + g * 4;
      float badd = bias[gcol];
#pragma unroll
      for (int r = 0; r < 4; r++)
        C[(size_t)(row0 + r) * 1024 + gcol] = acc[mt][nt][r] + badd;
    }
}

// --------------------------- flash attention (R14 body, bh-split) ------------
// Block: 128 q of one (b,h); 512 threads = 8 waves: wave w -> q-cols
// (w&3)*32, kv-half w>>2.  Each half: private K/V dbuf, kv-tile 64,
// 16 iters over its 1024 kv.  32x32x16 MFMA, P in registers (cvt_pk +
// permlane32_swap).  Static softmax => epilogue merges halves by addition.
// LDS: Ks 32K + Vs 32K = 64 KB.  Launched twice with bh0 = 0, 16.
__global__ __launch_bounds__(512, 4) void attn(
    const ushort* __restrict__ Qb,   // [4096][1024]  (pre-scaled)
    const ushort* __restrict__ Kb,   // [4096][1024]
    const ushort* __restrict__ Vt,   // [2][1024][2048]
    ushort* __restrict__ Ob,         // [4096][1024]
    int bh0) {
  __shared__ __align__(16) ushort Ks[2][2][64 * 64];  // [kvh][buf][kv][d] swz
  __shared__ __align__(16) ushort Vs[2][2][64 * 64];  // [kvh][buf][d][kv] swz

  const int bh = blockIdx.x + bh0, b = bh >> 4, h = bh & 15;
  const int q0 = blockIdx.y * 128;
  const int t = threadIdx.x, w = t >> 6, lane = t & 63;
  const int l31 = lane & 31, l5 = lane >> 5;
  const int qw = w & 3, kvh = w >> 2;
  const int th = t & 255;  // thread index within kv-half

  const ushort* Kg = Kb + (size_t)(b * 2048 + kvh * 1024) * 1024 + h * 64;
  const ushort* Vg = Vt + (size_t)(b * 1024 + h * 64) * 2048 + kvh * 1024;

  // Q B-frags: n = q = qw*32 + l31 ; k = ks*16 + l5*8 + j
  short8 bq[4];
  {
    int qa = q0 + qw * 32 + l31;
    const ushort* qrow = Qb + (size_t)(b * 2048 + qa) * 1024 + h * 64;
#pragma unroll
    for (int ks = 0; ks < 4; ks++)
      bq[ks] = *(const short8*)(qrow + ks * 16 + l5 * 8);
  }

  auto stageK = [&](int buf, int kv0) {  // kv0 relative to half base
#pragma unroll
    for (int p = 0; p < 2; p++) {
      int j = th + p * 256;              // 512 chunks: 64 rows x 8 slots
      int row = j >> 3, slot = j & 7, c = (slot - row) & 7;
      GLL(Kg + (size_t)(kv0 + row) * 1024 + c * 8, &Ks[kvh][buf][j * 8]);
    }
  };
  auto stageV = [&](int buf, int kv0) {
#pragma unroll
    for (int p = 0; p < 2; p++) {
      int j = th + p * 256;              // 512 chunks: 64 d-rows x 8 slots
      int row = j >> 3, slot = j & 7, c = (slot - row) & 7;
      GLL(Vg + (size_t)row * 2048 + kv0 + c * 8, &Vs[kvh][buf][j * 8]);
    }
  };
  stageK(0, 0);
  stageV(0, 0);

  floatx16 o2[2];
#pragma unroll
  for (int m2 = 0; m2 < 2; m2++)
#pragma unroll
    for (int r = 0; r < 16; r++) o2[m2][r] = 0.f;
  floatx4 l4 = {0.f, 0.f, 0.f, 0.f};

  for (int it = 0; it < 16; it++) {
    int cur = it & 1;
    __builtin_amdgcn_s_waitcnt(0);
    __syncthreads();  // K/V[cur] ready (both halves); all past [cur^1]
    if (it + 1 < 16) { stageK(cur ^ 1, (it + 1) * 64); stageV(cur ^ 1, (it + 1) * 64); }

    // Per 32-kv block: S^T = K @ Q^T (4 MFMA), exp, pack to PV B-frags.
    short8 bp[4];
#pragma unroll
    for (int m2 = 0; m2 < 2; m2++) {
      floatx16 s;
#pragma unroll
      for (int r = 0; r < 16; r++) s[r] = 0.f;
      int row = m2 * 32 + l31;
      __builtin_amdgcn_s_setprio(1);
#pragma unroll
      for (int ks = 0; ks < 4; ks++) {
        short8 a = *(const short8*)
            &Ks[kvh][cur][row * 64 + ((ks * 2 + l5 + row) & 7) * 8];
        s = __builtin_amdgcn_mfma_f32_32x32x16_bf16(a, bq[ks], s, 0, 0, 0);
      }
      __builtin_amdgcn_s_setprio(0);
#pragma unroll
      for (int r = 0; r < 16; r++) s[r] = EXP2(s[r]);
#pragma unroll
      for (int r = 0; r < 16; r++) l4[r & 3] += s[r];
      // lane reg r holds P[kv = m2*32 + (r&3)+8*(r>>2)+4*l5][q]
      unsigned pk[8];
#pragma unroll
      for (int p = 0; p < 8; p++)
        pk[p] = cvtpk(s[2 * p], s[2 * p + 1]);
#pragma unroll
      for (int hf = 0; hf < 2; hf++) {
        unsigned x0 = pk[hf * 4 + 0], y0 = pk[hf * 4 + 2];
        unsigned x1 = pk[hf * 4 + 1], y1 = pk[hf * 4 + 3];
        asm("v_permlane32_swap_b32 %0, %1" : "+v"(x0), "+v"(y0));
        asm("v_permlane32_swap_b32 %0, %1" : "+v"(x1), "+v"(y1));
        union { unsigned u[4]; short8 s8; } fu;
        fu.u[0] = x0; fu.u[1] = x1; fu.u[2] = y0; fu.u[3] = y1;
        bp[m2 * 2 + hf] = fu.s8;  // kv = kt*16 + l5*8 + j, kt = m2*2+hf
      }
    }

    // O^T += V^T @ P^T : 8 MFMA
    __builtin_amdgcn_s_setprio(1);
#pragma unroll
    for (int kt = 0; kt < 4; kt++)
#pragma unroll
      for (int m2 = 0; m2 < 2; m2++) {
        int row = m2 * 32 + l31;
        short8 av = *(const short8*)
            &Vs[kvh][cur][row * 64 + ((kt * 2 + l5 + row) & 7) * 8];
        o2[m2] = __builtin_amdgcn_mfma_f32_32x32x16_bf16(av, bp[kt], o2[m2], 0, 0, 0);
      }
    __builtin_amdgcn_s_setprio(0);
  }

  // per-lane partial l (this wave's kv-half, l5-split of rows)
  float lp = (l4[0] + l4[1]) + (l4[2] + l4[3]);

  // ---- merge the two kv-halves: o_tot = o_h0 + o_h1, l_tot = l_h0 + l_h1 --
  __syncthreads();  // all waves done with Ks/Vs
  float2* Of = (float2*)&Ks[0][0][0];  // [16 idx-pairs][256 lanes] = 32 KB
  float*  Lf = (float*)&Vs[0][0][0];   // [256 lanes] = 1 KB
  if (kvh == 1) {
#pragma unroll
    for (int m2 = 0; m2 < 2; m2++)
#pragma unroll
      for (int p = 0; p < 8; p++) {
        float2 v = {o2[m2][2 * p], o2[m2][2 * p + 1]};
        Of[(m2 * 8 + p) * 256 + qw * 64 + lane] = v;
      }
    Lf[qw * 64 + lane] = lp;
  }
  __syncthreads();
  if (kvh == 0) {
#pragma unroll
    for (int m2 = 0; m2 < 2; m2++)
#pragma unroll
      for (int p = 0; p < 8; p++) {
        float2 v = Of[(m2 * 8 + p) * 256 + qw * 64 + lane];
        o2[m2][2 * p] += v.x;
        o2[m2][2 * p + 1] += v.y;
      }
    lp += Lf[qw * 64 + lane];
  }
  float l = lp + __shfl_xor(lp, 32);
  float inv_l = 1.f / l;

  // epilogue (waves 0-3): normalize, O^T -> O via LDS, write bf16
  __syncthreads();  // Of reads done; Ks reusable as Ot
  ushort* Ot = &Ks[0][0][0];  // [128 q][64 d], 16 KB, 8B-slot swizzle
  if (kvh == 0) {
    int q = qw * 32 + l31;
#pragma unroll
    for (int m2 = 0; m2 < 2; m2++)
#pragma unroll
      for (int pp = 0; pp < 4; pp++) {
        // regs 4pp..4pp+3 -> d = m2*32 + 8*pp + 4*l5 + 0..3
        uint2 pk2;
        pk2.x = cvtpk(o2[m2][4 * pp + 0] * inv_l, o2[m2][4 * pp + 1] * inv_l);
        pk2.y = cvtpk(o2[m2][4 * pp + 2] * inv_l, o2[m2][4 * pp + 3] * inv_l);
        int s = m2 * 8 + 2 * pp + l5;  // 4-ushort slot index, 0..15
        *(uint2*)&Ot[q * 64 + ((s + q) & 15) * 4] = pk2;
      }
  }
  asm volatile("" ::: "memory");  // rows wave-private; order write->read
  if (kvh == 0) {
#pragma unroll
    for (int p = 0; p < 4; p++) {
      int j = lane + p * 64;
      int r32 = j >> 3, c = j & 7;  // 32 q rows x 8 chunks per wave
      int qr = qw * 32 + r32;
      short4v lo = *(const short4v*)&Ot[qr * 64 + ((2 * c + qr) & 15) * 4];
      short4v hi = *(const short4v*)&Ot[qr * 64 + ((2 * c + 1 + qr) & 15) * 4];
      short8 v = {lo.x, lo.y, lo.z, lo.w, hi.x, hi.y, hi.z, hi.w};
      *(short8*)(Ob + (size_t)(b * 2048 + q0 + qr) * 1024 + h * 64 + c * 8) = v;
    }
  }
}

// ---------------------------------------------------------------------------
extern "C" void kernel_launch(void* const* d_in, const int* in_sizes, int n_in,
                              void* d_out, int out_size, void* d_ws, size_t ws_size,
                              hipStream_t stream) {
  const float* x_q  = (const float*)d_in[0];
  const float* x_kv = (const float*)d_in[1];
  const float* Wqkv = (const float*)d_in[2];
  const float* Wout = (const float*)d_in[3];
  const float* bout = (const float*)d_in[4];
  float* out = (float*)d_out;

  char* p = (char*)d_ws;  // 56 MiB total
  ushort* Xq    = (ushort*)p; p += (size_t)4096 * 1024 * 2;
  ushort* Xkv   = (ushort*)p; p += (size_t)4096 * 1024 * 2;
  ushort* WqkvT = (ushort*)p; p += (size_t)3072 * 1024 * 2;
  ushort* WoutT = (ushort*)p; p += (size_t)1024 * 1024 * 2;
  ushort* Qb    = (ushort*)p; p += (size_t)4096 * 1024 * 2;
  ushort* Kb    = (ushort*)p; p += (size_t)4096 * 1024 * 2;
  ushort* Vt    = (ushort*)p; p += (size_t)2 * 1024 * 2048 * 2;
  ushort* Ob    = (ushort*)p; p += (size_t)4096 * 1024 * 2;

  prep<<<6144, 256, 0, stream>>>(x_q, x_kv, Xq, Xkv, Wqkv, WqkvT, Wout, WoutT);
  gemm_qkv<<<dim3(24, 32), 256, 0, stream>>>(Xq, Xkv, WqkvT, Qb, Kb, Vt);
  attn<<<dim3(16, 16), 512, 0, stream>>>(Qb, Kb, Vt, Ob, 0);
  attn<<<dim3(16, 16), 512, 0, stream>>>(Qb, Kb, Vt, Ob, 16);
  gemm_out<<<dim3(16, 32), 256, 0, stream>>>(Ob, WoutT, out, bout);
}

// Round 9
// 182.887 us; speedup vs baseline: 1.1166x; 1.1166x over previous
//
#include <hip/hip_runtime.h>

// ---------------------------------------------------------------------------
// Attention (b=2, sq=skv=2048, dim=1024, H=16, DH=64) for MI355X / gfx950.
// fp32 -> bf16 internal -> fp32 out.  4 dispatches:
//   prep (cvt x2 + transpose W) | fused QKV GEMM | attn | GEMM out
// R18 = R17 resubmit (bench died at container level, no kernel data).
//   GEMMs use T4 counted-vmcnt pipelining: 3 LDS buffers, raw s_barrier
//   (no compiler vmcnt(0) drain), s_waitcnt vmcnt(4)/(3) so the newest
//   stage's loads stay in flight across the barrier.  R16 exposed
//   gemm_qkv = 44us (586 TF-equiv, MfmaUtil 21.6, nothing saturated) --
//   the 2-barrier drain stall at short K.  attn single dispatch (R14 body).
// ---------------------------------------------------------------------------

typedef __attribute__((ext_vector_type(8))) short short8;   // 8 x bf16
typedef __attribute__((ext_vector_type(4))) short short4v;  // 4 x bf16 (8B)
typedef __attribute__((ext_vector_type(4))) float floatx4;  // MFMA accum 16x16
typedef __attribute__((ext_vector_type(16))) float floatx16; // MFMA accum 32x32

#define QSCALE 0.18033688f  /* 0.125 * log2(e) folded into Q */

#if __has_builtin(__builtin_amdgcn_exp2f)
#define EXP2(x) __builtin_amdgcn_exp2f(x)
#else
#define EXP2(x) exp2f(x)
#endif

__device__ __forceinline__ ushort f2b(float f) {  // fp32 -> bf16 RNE
  union { float f; unsigned u; } x; x.f = f;
  unsigned r = (x.u + 0x7fffu + ((x.u >> 16) & 1u)) >> 16;
  return (ushort)r;
}

// pack two fp32 -> two bf16 (RNE), single instruction; a -> low ushort
__device__ __forceinline__ unsigned cvtpk(float a, float b) {
  unsigned r;
  asm("v_cvt_pk_bf16_f32 %0, %1, %2" : "=v"(r) : "v"(a), "v"(b));
  return r;
}

#define GLL(gp, lp)                                                            \
  __builtin_amdgcn_global_load_lds(                                            \
      (const __attribute__((address_space(1))) void*)(gp),                     \
      (__attribute__((address_space(3))) void*)(lp), 16, 0, 0)

// ---- prep: activations fp32->bf16 (blocks 0..2047) + W transpose (rest) ----
__global__ void prep(const float* __restrict__ xq, const float* __restrict__ xkv,
                     ushort* __restrict__ oq, ushort* __restrict__ okv,
                     const float* __restrict__ Wqkv, ushort* __restrict__ WqkvT,
                     const float* __restrict__ Wout, ushort* __restrict__ WoutT) {
  __shared__ float tile[32][33];
  int bid = blockIdx.x;
  const int n = 4096 * 1024;
  if (bid < 2048) {
    bool lo = bid < 1024;
    const float* in = lo ? xq : xkv;
    ushort* out = lo ? oq : okv;
    int b2 = lo ? bid : bid - 1024;
    int stride = 1024 * 256 * 4;
    for (int i = (b2 * 256 + (int)threadIdx.x) * 4; i < n; i += stride) {
      float4 v = *(const float4*)(in + i);
      uint2 o;
      o.x = cvtpk(v.x, v.y);
      o.y = cvtpk(v.z, v.w);
      *(uint2*)(out + i) = o;
    }
    return;
  }
  // transpose blocks: 4096 tiles of 32x32 (96+32 cols x 32 rows of k)
  int tb = bid - 2048;               // 0..4095
  int bx = tb & 127, by = tb >> 7;   // bx: 0..95 Wqkv, 96..127 Wout
  bool first = bx < 96;
  const float* in = first ? Wqkv : Wout;
  ushort* out = first ? WqkvT : WoutT;
  int N = first ? 3072 : 1024;
  int bxx = first ? bx : bx - 96;
  int k0 = by * 32, n0 = bxx * 32;
  // load: 256 thr = 32 k-rows x 8 float4-cols, coalesced 16B
  {
    int row = threadIdx.x >> 3, c = threadIdx.x & 7;
    float4 v = *(const float4*)(in + (size_t)(k0 + row) * N + n0 + c * 4);
    tile[row][c * 4 + 0] = v.x;
    tile[row][c * 4 + 1] = v.y;
    tile[row][c * 4 + 2] = v.z;
    tile[row][c * 4 + 3] = v.w;
  }
  __syncthreads();
  // store: 256 thr = 16 k-pairs x 16 n-rows, dword (2 bf16) stores
  {
    int tx2 = threadIdx.x & 15, ty2 = threadIdx.x >> 4;
#pragma unroll
    for (int i = 0; i < 2; i++) {
      int nr = ty2 + 16 * i;
      unsigned v = cvtpk(tile[2 * tx2][nr], tile[2 * tx2 + 1][nr]);
      *(unsigned*)(out + (size_t)(n0 + nr) * 1024 + k0 + 2 * tx2) = v;
    }
  }
}

// ------- fused QKV GEMM: 128x128 tile, BK=32, 3-buf counted-vmcnt (T4) ------
// C cols: [0,1024) Q*QSCALE -> Cq ; [1024,2048) K -> Ck ; [2048,3072) V^T -> Cv
// Per iter: s_waitcnt vmcnt(4) (oldest stage landed; newest stays in flight)
// + raw s_barrier + stage(i+2) + compute(i).  No vmcnt(0) drain in the loop.
__global__ __launch_bounds__(256, 3) void gemm_qkv(
    const ushort* __restrict__ Aq, const ushort* __restrict__ Akv,
    const ushort* __restrict__ Bt,
    ushort* __restrict__ Cq, ushort* __restrict__ Ck, ushort* __restrict__ Cv) {
  __shared__ __align__(16) ushort smem[24576];  // 48 KB: 3 x (A 8K + B 8K)
  ushort* Asb = smem;           // [3][4096]
  ushort* Bsb = smem + 12288;   // [3][4096]
  // swizzle: lid -> xcd-chunked id; bx 0..23 (n), by 0..31 (m)
  int lid = blockIdx.y * 24 + blockIdx.x;
  int nid = (lid & 7) * 96 + (lid >> 3);
  int bx = nid % 24, by = nid / 24;
  const int n0 = bx * 128, m0 = by * 128;
  // col blocks: 0..7 = Q (from x_q), 8..15 = K, 16..23 = V (both from x_kv)
  const ushort* A = (bx >= 8) ? Akv : Aq;
  const int t = threadIdx.x;
  const int w = t >> 6, lane = t & 63, dl = lane & 15, g = lane >> 4;
  const int wm = (w >> 1) * 64, wn = (w & 1) * 64;
  const int K = 1024;

  auto stage = [&](int buf, int k0) {  // 4 GLL / thread
#pragma unroll
    for (int p = 0; p < 2; p++) {
      int j = t + p * 256;
      int row = j >> 2, slot = j & 3, c = (slot - row) & 3;
      GLL(A + (size_t)(m0 + row) * K + k0 + c * 8, &Asb[buf * 4096 + j * 8]);
    }
#pragma unroll
    for (int p = 0; p < 2; p++) {
      int j = t + p * 256;
      int row = j >> 2, slot = j & 3, c = (slot - row) & 3;
      GLL(Bt + (size_t)(n0 + row) * K + k0 + c * 8, &Bsb[buf * 4096 + j * 8]);
    }
  };

  const floatx4 fz = {0.f, 0.f, 0.f, 0.f};
  floatx4 acc[4][4];
#pragma unroll
  for (int i = 0; i < 4; i++)
#pragma unroll
    for (int j = 0; j < 4; j++) acc[i][j] = fz;

  stage(0, 0);
  stage(1, 32);
  int cur = 0;
  for (int kt = 0; kt < 32; kt++) {
    if (kt + 1 < 32) asm volatile("s_waitcnt vmcnt(4)" ::: "memory");
    else             asm volatile("s_waitcnt vmcnt(0)" ::: "memory");
    __builtin_amdgcn_s_barrier();   // raw: no compiler-inserted drain
    __builtin_amdgcn_sched_barrier(0);
    if (kt + 2 < 32) {
      int nb = (cur >= 1) ? cur - 1 : cur + 2;  // (cur+2)%3
      stage(nb, (kt + 2) * 32);
    }
    short8 af[4], bf[4];
#pragma unroll
    for (int mt = 0; mt < 4; mt++) {
      int row = wm + mt * 16 + dl;
      af[mt] = *(const short8*)&Asb[cur * 4096 + row * 32 + ((g + row) & 3) * 8];
    }
#pragma unroll
    for (int nt = 0; nt < 4; nt++) {
      int row = wn + nt * 16 + dl;
      bf[nt] = *(const short8*)&Bsb[cur * 4096 + row * 32 + ((g + row) & 3) * 8];
    }
#pragma unroll
    for (int mt = 0; mt < 4; mt++)
#pragma unroll
      for (int nt = 0; nt < 4; nt++)
        acc[mt][nt] = __builtin_amdgcn_mfma_f32_16x16x32_bf16(af[mt], bf[nt], acc[mt][nt], 0, 0, 0);
    cur = (cur < 2) ? cur + 1 : 0;
  }

  if (bx < 16) {
    // direct store: row = g*4 + r (+16*mt), col = dl (+16*nt)
#pragma unroll
    for (int mt = 0; mt < 4; mt++)
#pragma unroll
      for (int nt = 0; nt < 4; nt++) {
        int gcol = n0 + wn + nt * 16 + dl;
        int row0 = m0 + wm + mt * 16 + g * 4;
        if (gcol < 1024) {  // Q with folded softmax scale
#pragma unroll
          for (int r = 0; r < 4; r++)
            Cq[(size_t)(row0 + r) * 1024 + gcol] =
                (ushort)cvtpk(acc[mt][nt][r] * QSCALE, 0.f);
        } else {
#pragma unroll
          for (int r = 0; r < 4; r++)
            Ck[(size_t)(row0 + r) * 1024 + gcol - 1024] =
                (ushort)cvtpk(acc[mt][nt][r], 0.f);
        }
      }
  } else {
    // V^T via LDS: smem tile [n-local 128][m-local, stride 136] bf16
    __syncthreads();  // loop ended with vmcnt(0); all reads done; reuse smem
#pragma unroll
    for (int mt = 0; mt < 4; mt++)
#pragma unroll
      for (int nt = 0; nt < 4; nt++) {
        int ncol = wn + nt * 16 + dl;     // hd-local
        int mrow = wm + mt * 16 + g * 4;  // kv-local (4 consecutive)
        uint2 pk;
        pk.x = cvtpk(acc[mt][nt][0], acc[mt][nt][1]);
        pk.y = cvtpk(acc[mt][nt][2], acc[mt][nt][3]);
        *(uint2*)&smem[ncol * 136 + mrow] = pk;
      }
    __syncthreads();
    // coalesced: Cv[b][hd][kv], 2048 chunks of 16B (128 rows x 16 chunks)
    int hd0 = n0 - 2048;            // 0..1023
    int bb = m0 >> 11;              // batch
    int kv0 = m0 & 2047;
#pragma unroll
    for (int p = 0; p < 8; p++) {
      int j = t + p * 256;
      int row = j >> 4, c = j & 15;
      short8 v = *(const short8*)&smem[row * 136 + c * 8];
      *(short8*)(Cv + ((size_t)(bb * 1024 + hd0 + row)) * 2048 + kv0 + c * 8) = v;
    }
  }
}

// ---- out GEMM: 128x64 tile, BK=32, 3-buf counted-vmcnt (T4), f32 + bias ----
__global__ __launch_bounds__(256, 3) void gemm_out(
    const ushort* __restrict__ A, const ushort* __restrict__ Bt,
    float* __restrict__ C, const float* __restrict__ bias) {
  __shared__ __align__(16) ushort smem[18432];  // 36 KB: 3 x (A 8KB + B 4KB)
  ushort* As3 = smem;           // [3][4096]
  ushort* Bs3 = smem + 12288;   // [3][2048]
  // swizzle: 512 blocks, 64/XCD
  int lid = blockIdx.y * 16 + blockIdx.x;
  int nid = (lid & 7) * 64 + (lid >> 3);
  int bx = nid & 15, by = nid >> 4;
  const int n0 = bx * 64, m0 = by * 128;
  const int t = threadIdx.x;
  const int w = t >> 6, lane = t & 63, dl = lane & 15, g = lane >> 4;
  const int wm = (w >> 1) * 64, wn = (w & 1) * 32;
  const int K = 1024;

  auto stage = [&](int buf, int k0) {  // 3 GLL / thread
#pragma unroll
    for (int p = 0; p < 2; p++) {
      int j = t + p * 256;
      int row = j >> 2, slot = j & 3, c = (slot - row) & 3;
      GLL(A + (size_t)(m0 + row) * K + k0 + c * 8, &As3[buf * 4096 + j * 8]);
    }
    {
      int j = t;  // 256 chunks: 64 rows x 4 slots
      int row = j >> 2, slot = j & 3, c = (slot - row) & 3;
      GLL(Bt + (size_t)(n0 + row) * K + k0 + c * 8, &Bs3[buf * 2048 + j * 8]);
    }
  };

  const floatx4 fz = {0.f, 0.f, 0.f, 0.f};
  floatx4 acc[4][2];
#pragma unroll
  for (int i = 0; i < 4; i++)
#pragma unroll
    for (int j = 0; j < 2; j++) acc[i][j] = fz;

  stage(0, 0);
  stage(1, 32);
  int cur = 0;
  for (int kt = 0; kt < 32; kt++) {
    if (kt + 1 < 32) asm volatile("s_waitcnt vmcnt(3)" ::: "memory");
    else             asm volatile("s_waitcnt vmcnt(0)" ::: "memory");
    __builtin_amdgcn_s_barrier();
    __builtin_amdgcn_sched_barrier(0);
    if (kt + 2 < 32) {
      int nb = (cur >= 1) ? cur - 1 : cur + 2;  // (cur+2)%3
      stage(nb, (kt + 2) * 32);
    }
    short8 af[4], bf[2];
#pragma unroll
    for (int mt = 0; mt < 4; mt++) {
      int row = wm + mt * 16 + dl;
      af[mt] = *(const short8*)&As3[cur * 4096 + row * 32 + ((g + row) & 3) * 8];
    }
#pragma unroll
    for (int nt = 0; nt < 2; nt++) {
      int row = wn + nt * 16 + dl;
      bf[nt] = *(const short8*)&Bs3[cur * 2048 + row * 32 + ((g + row) & 3) * 8];
    }
#pragma unroll
    for (int mt = 0; mt < 4; mt++)
#pragma unroll
      for (int nt = 0; nt < 2; nt++)
        acc[mt][nt] = __builtin_amdgcn_mfma_f32_16x16x32_bf16(af[mt], bf[nt], acc[mt][nt], 0, 0, 0);
    cur = (cur < 2) ? cur + 1 : 0;
  }
#pragma unroll
  for (int mt = 0; mt < 4; mt++)
#pragma unroll
    for (int nt = 0; nt < 2; nt++) {
      int gcol = n0 + wn + nt * 16 + dl;
      int row0 = m0 + wm + mt * 16 + g * 4;
      float badd = bias[gcol];
#pragma unroll
      for (int r = 0; r < 4; r++)
        C[(size_t)(row0 + r) * 1024 + gcol] = acc[mt][nt][r] + badd;
    }
}

// --------------------------- flash attention (R14 best) ----------------------
// Block: 128 q of one (b,h); 512 threads = 8 waves: wave w -> q-cols
// (w&3)*32, kv-half w>>2.  Each half: private K/V dbuf, kv-tile 64,
// 16 iters over its 1024 kv.  32x32x16 MFMA, P in registers (cvt_pk +
// permlane32_swap).  Static softmax => epilogue merges halves by addition.
// LDS: Ks 32K + Vs 32K = 64 KB -> 2 blocks/CU, 4 waves/SIMD.
__global__ __launch_bounds__(512, 4) void attn(
    const ushort* __restrict__ Qb,   // [4096][1024]  (pre-scaled)
    const ushort* __restrict__ Kb,   // [4096][1024]
    const ushort* __restrict__ Vt,   // [2][1024][2048]
    ushort* __restrict__ Ob) {       // [4096][1024]
  __shared__ __align__(16) ushort Ks[2][2][64 * 64];  // [kvh][buf][kv][d] swz
  __shared__ __align__(16) ushort Vs[2][2][64 * 64];  // [kvh][buf][d][kv] swz

  const int bh = blockIdx.x, b = bh >> 4, h = bh & 15;
  const int q0 = blockIdx.y * 128;
  const int t = threadIdx.x, w = t >> 6, lane = t & 63;
  const int l31 = lane & 31, l5 = lane >> 5;
  const int qw = w & 3, kvh = w >> 2;
  const int th = t & 255;  // thread index within kv-half

  const ushort* Kg = Kb + (size_t)(b * 2048 + kvh * 1024) * 1024 + h * 64;
  const ushort* Vg = Vt + (size_t)(b * 1024 + h * 64) * 2048 + kvh * 1024;

  // Q B-frags: n = q = qw*32 + l31 ; k = ks*16 + l5*8 + j
  short8 bq[4];
  {
    int qa = q0 + qw * 32 + l31;
    const ushort* qrow = Qb + (size_t)(b * 2048 + qa) * 1024 + h * 64;
#pragma unroll
    for (int ks = 0; ks < 4; ks++)
      bq[ks] = *(const short8*)(qrow + ks * 16 + l5 * 8);
  }

  auto stageK = [&](int buf, int kv0) {  // kv0 relative to half base
#pragma unroll
    for (int p = 0; p < 2; p++) {
      int j = th + p * 256;              // 512 chunks: 64 rows x 8 slots
      int row = j >> 3, slot = j & 7, c = (slot - row) & 7;
      GLL(Kg + (size_t)(kv0 + row) * 1024 + c * 8, &Ks[kvh][buf][j * 8]);
    }
  };
  auto stageV = [&](int buf, int kv0) {
#pragma unroll
    for (int p = 0; p < 2; p++) {
      int j = th + p * 256;              // 512 chunks: 64 d-rows x 8 slots
      int row = j >> 3, slot = j & 7, c = (slot - row) & 7;
      GLL(Vg + (size_t)row * 2048 + kv0 + c * 8, &Vs[kvh][buf][j * 8]);
    }
  };
  stageK(0, 0);
  stageV(0, 0);

  floatx16 o2[2];
#pragma unroll
  for (int m2 = 0; m2 < 2; m2++)
#pragma unroll
    for (int r = 0; r < 16; r++) o2[m2][r] = 0.f;
  floatx4 l4 = {0.f, 0.f, 0.f, 0.f};

  for (int it = 0; it < 16; it++) {
    int cur = it & 1;
    __builtin_amdgcn_s_waitcnt(0);
    __syncthreads();  // K/V[cur] ready (both halves); all past [cur^1]
    if (it + 1 < 16) { stageK(cur ^ 1, (it + 1) * 64); stageV(cur ^ 1, (it + 1) * 64); }

    // Per 32-kv block: S^T = K @ Q^T (4 MFMA), exp, pack to PV B-frags.
    short8 bp[4];
#pragma unroll
    for (int m2 = 0; m2 < 2; m2++) {
      floatx16 s;
#pragma unroll
      for (int r = 0; r < 16; r++) s[r] = 0.f;
      int row = m2 * 32 + l31;
      __builtin_amdgcn_s_setprio(1);
#pragma unroll
      for (int ks = 0; ks < 4; ks++) {
        short8 a = *(const short8*)
            &Ks[kvh][cur][row * 64 + ((ks * 2 + l5 + row) & 7) * 8];
        s = __builtin_amdgcn_mfma_f32_32x32x16_bf16(a, bq[ks], s, 0, 0, 0);
      }
      __builtin_amdgcn_s_setprio(0);
#pragma unroll
      for (int r = 0; r < 16; r++) s[r] = EXP2(s[r]);
#pragma unroll
      for (int r = 0; r < 16; r++) l4[r & 3] += s[r];
      // lane reg r holds P[kv = m2*32 + (r&3)+8*(r>>2)+4*l5][q]
      unsigned pk[8];
#pragma unroll
      for (int p = 0; p < 8; p++)
        pk[p] = cvtpk(s[2 * p], s[2 * p + 1]);
#pragma unroll
      for (int hf = 0; hf < 2; hf++) {
        unsigned x0 = pk[hf * 4 + 0], y0 = pk[hf * 4 + 2];
        unsigned x1 = pk[hf * 4 + 1], y1 = pk[hf * 4 + 3];
        asm("v_permlane32_swap_b32 %0, %1" : "+v"(x0), "+v"(y0));
        asm("v_permlane32_swap_b32 %0, %1" : "+v"(x1), "+v"(y1));
        union { unsigned u[4]; short8 s8; } fu;
        fu.u[0] = x0; fu.u[1] = x1; fu.u[2] = y0; fu.u[3] = y1;
        bp[m2 * 2 + hf] = fu.s8;  // kv = kt*16 + l5*8 + j, kt = m2*2+hf
      }
    }

    // O^T += V^T @ P^T : 8 MFMA
    __builtin_amdgcn_s_setprio(1);
#pragma unroll
    for (int kt = 0; kt < 4; kt++)
#pragma unroll
      for (int m2 = 0; m2 < 2; m2++) {
        int row = m2 * 32 + l31;
        short8 av = *(const short8*)
            &Vs[kvh][cur][row * 64 + ((kt * 2 + l5 + row) & 7) * 8];
        o2[m2] = __builtin_amdgcn_mfma_f32_32x32x16_bf16(av, bp[kt], o2[m2], 0, 0, 0);
      }
    __builtin_amdgcn_s_setprio(0);
  }

  // per-lane partial l (this wave's kv-half, l5-split of rows)
  float lp = (l4[0] + l4[1]) + (l4[2] + l4[3]);

  // ---- merge the two kv-halves: o_tot = o_h0 + o_h1, l_tot = l_h0 + l_h1 --
  __syncthreads();  // all waves done with Ks/Vs
  float2* Of = (float2*)&Ks[0][0][0];  // [16 idx-pairs][256 lanes] = 32 KB
  float*  Lf = (float*)&Vs[0][0][0];   // [256 lanes] = 1 KB
  if (kvh == 1) {
#pragma unroll
    for (int m2 = 0; m2 < 2; m2++)
#pragma unroll
      for (int p = 0; p < 8; p++) {
        float2 v = {o2[m2][2 * p], o2[m2][2 * p + 1]};
        Of[(m2 * 8 + p) * 256 + qw * 64 + lane] = v;
      }
    Lf[qw * 64 + lane] = lp;
  }
  __syncthreads();
  if (kvh == 0) {
#pragma unroll
    for (int m2 = 0; m2 < 2; m2++)
#pragma unroll
      for (int p = 0; p < 8; p++) {
        float2 v = Of[(m2 * 8 + p) * 256 + qw * 64 + lane];
        o2[m2][2 * p] += v.x;
        o2[m2][2 * p + 1] += v.y;
      }
    lp += Lf[qw * 64 + lane];
  }
  float l = lp + __shfl_xor(lp, 32);
  float inv_l = 1.f / l;

  // epilogue (waves 0-3): normalize, O^T -> O via LDS, write bf16
  __syncthreads();  // Of reads done; Ks reusable as Ot
  ushort* Ot = &Ks[0][0][0];  // [128 q][64 d], 16 KB, 8B-slot swizzle
  if (kvh == 0) {
    int q = qw * 32 + l31;
#pragma unroll
    for (int m2 = 0; m2 < 2; m2++)
#pragma unroll
      for (int pp = 0; pp < 4; pp++) {
        // regs 4pp..4pp+3 -> d = m2*32 + 8*pp + 4*l5 + 0..3
        uint2 pk2;
        pk2.x = cvtpk(o2[m2][4 * pp + 0] * inv_l, o2[m2][4 * pp + 1] * inv_l);
        pk2.y = cvtpk(o2[m2][4 * pp + 2] * inv_l, o2[m2][4 * pp + 3] * inv_l);
        int s = m2 * 8 + 2 * pp + l5;  // 4-ushort slot index, 0..15
        *(uint2*)&Ot[q * 64 + ((s + q) & 15) * 4] = pk2;
      }
  }
  asm volatile("" ::: "memory");  // rows wave-private; order write->read
  if (kvh == 0) {
#pragma unroll
    for (int p = 0; p < 4; p++) {
      int j = lane + p * 64;
      int r32 = j >> 3, c = j & 7;  // 32 q rows x 8 chunks per wave
      int qr = qw * 32 + r32;
      short4v lo = *(const short4v*)&Ot[qr * 64 + ((2 * c + qr) & 15) * 4];
      short4v hi = *(const short4v*)&Ot[qr * 64 + ((2 * c + 1 + qr) & 15) * 4];
      short8 v = {lo.x, lo.y, lo.z, lo.w, hi.x, hi.y, hi.z, hi.w};
      *(short8*)(Ob + (size_t)(b * 2048 + q0 + qr) * 1024 + h * 64 + c * 8) = v;
    }
  }
}

// ---------------------------------------------------------------------------
extern "C" void kernel_launch(void* const* d_in, const int* in_sizes, int n_in,
                              void* d_out, int out_size, void* d_ws, size_t ws_size,
                              hipStream_t stream) {
  const float* x_q  = (const float*)d_in[0];
  const float* x_kv = (const float*)d_in[1];
  const float* Wqkv = (const float*)d_in[2];
  const float* Wout = (const float*)d_in[3];
  const float* bout = (const float*)d_in[4];
  float* out = (float*)d_out;

  char* p = (char*)d_ws;  // 56 MiB total
  ushort* Xq    = (ushort*)p; p += (size_t)4096 * 1024 * 2;
  ushort* Xkv   = (ushort*)p; p += (size_t)4096 * 1024 * 2;
  ushort* WqkvT = (ushort*)p; p += (size_t)3072 * 1024 * 2;
  ushort* WoutT = (ushort*)p; p += (size_t)1024 * 1024 * 2;
  ushort* Qb    = (ushort*)p; p += (size_t)4096 * 1024 * 2;
  ushort* Kb    = (ushort*)p; p += (size_t)4096 * 1024 * 2;
  ushort* Vt    = (ushort*)p; p += (size_t)2 * 1024 * 2048 * 2;
  ushort* Ob    = (ushort*)p; p += (size_t)4096 * 1024 * 2;

  prep<<<6144, 256, 0, stream>>>(x_q, x_kv, Xq, Xkv, Wqkv, WqkvT, Wout, WoutT);
  gemm_qkv<<<dim3(24, 32), 256, 0, stream>>>(Xq, Xkv, WqkvT, Qb, Kb, Vt);
  attn<<<dim3(32, 16), 512, 0, stream>>>(Qb, Kb, Vt, Ob);
  gemm_out<<<dim3(16, 32), 256, 0, stream>>>(Ob, WoutT, out, bout);
}